// Round 3
// baseline (684.996 us; speedup 1.0000x reference)
//
#include <hip/hip_runtime.h>
#include <hip/hip_bf16.h>
#include <stdint.h>

#define VOCAB 32000
#define HID   256
#define BATCH 16
#define SEQT  256
#define ROWS  (BATCH*SEQT)   // 4096

typedef __attribute__((ext_vector_type(8))) short bf16x8_t;
typedef __attribute__((ext_vector_type(4))) float f32x4_t;

__device__ __forceinline__ short f2bs(float x) {
    __hip_bfloat16 h = __float2bfloat16(x);
    return *reinterpret_cast<short*>(&h);
}
__device__ __forceinline__ float bs2f(short s) {
    __hip_bfloat16 h = *reinterpret_cast<__hip_bfloat16*>(&s);
    return __bfloat162float(h);
}
__device__ __forceinline__ bf16x8_t cvt8(float4 a, float4 b) {
    union { short s[8]; bf16x8_t v; } u;
    u.s[0] = f2bs(a.x); u.s[1] = f2bs(a.y); u.s[2] = f2bs(a.z); u.s[3] = f2bs(a.w);
    u.s[4] = f2bs(b.x); u.s[5] = f2bs(b.y); u.s[6] = f2bs(b.z); u.s[7] = f2bs(b.w);
    return u.v;
}
__device__ __forceinline__ float tanh_fast(float x) {
    float e = __expf(2.0f * x);
    return 1.0f - 2.0f / (e + 1.0f);
}

// ---------------------------------------------------------------------------
// K0: zero S[4096] (d_ws is re-poisoned 0xAA before every timed launch)
// ---------------------------------------------------------------------------
__global__ __launch_bounds__(256) void zinit_kernel(float* __restrict__ S) {
    S[blockIdx.x * 256 + threadIdx.x] = 0.0f;
}

// ---------------------------------------------------------------------------
// K1: RNN recurrence with fused embedding gather. All float inputs are fp32.
// One block, 512 threads (8 waves). M=16 (batch), N=K=256 (hidden).
// Whh converted to bf16 B-fragments in registers once; h lives in LDS (bf16).
// x_t = Wih[inputs[:,t]] + bih + bhh   (fp32, prefetched 1 step ahead)
// h_t = tanh(x_t + h_{t-1} @ Whh^T) -> hs[b][t][h] (bf16, for the FC GEMM)
// ---------------------------------------------------------------------------
__global__ __launch_bounds__(512, 1) void rnn_kernel(
    const int* __restrict__ inputs,
    const float* __restrict__ Wih,
    const float* __restrict__ bih,
    const float* __restrict__ bhh,
    const float* __restrict__ Whh,
    __hip_bfloat16* __restrict__ hs)
{
    __shared__ short hbuf[16][264];       // bf16 bits of h_{t-1}; +8 pad
    __shared__ int   ids[SEQT * BATCH];   // ids[t*16+b]
    const int tid = threadIdx.x;
    const int l = tid & 63, w = tid >> 6;
    const int lr = l & 15, lh = l >> 4;

    for (int i = tid; i < SEQT * BATCH; i += 512) {
        int t = i >> 4, b = i & 15;
        ids[i] = inputs[b * SEQT + t];
    }
    for (int i = tid; i < 16 * 264; i += 512) ((short*)hbuf)[i] = 0;

    // B fragments: B[k][n] = Whh[n][k]; lane n = w*32+nt*16+lr, k = ki*32+lh*8+j
    bf16x8_t bfrag[2][8];
    float bb[2];
#pragma unroll
    for (int nt = 0; nt < 2; nt++) {
        int n = w * 32 + nt * 16 + lr;
        bb[nt] = bih[n] + bhh[n];
#pragma unroll
        for (int ki = 0; ki < 8; ki++) {
            const float4* p = (const float4*)(Whh + n * HID + ki * 32 + lh * 8);
            bfrag[nt][ki] = cvt8(p[0], p[1]);
        }
    }
    __syncthreads();

    // prefetch x for t=0: rows m = lh*4+r, cols n = w*32+nt*16+lr
    float xv[2][4];
#pragma unroll
    for (int nt = 0; nt < 2; nt++) {
        int n = w * 32 + nt * 16 + lr;
#pragma unroll
        for (int r = 0; r < 4; r++)
            xv[nt][r] = Wih[(size_t)ids[lh * 4 + r] * HID + n] + bb[nt];
    }

    for (int t = 0; t < SEQT; t++) {
        // A fragments from LDS: A[m=lr][k=ki*32+lh*8+j]
        bf16x8_t afr[8];
#pragma unroll
        for (int ki = 0; ki < 8; ki++)
            afr[ki] = *(const bf16x8_t*)(&hbuf[lr][ki * 32 + lh * 8]);

        f32x4_t acc0 = {0.f, 0.f, 0.f, 0.f}, acc1 = {0.f, 0.f, 0.f, 0.f};
#pragma unroll
        for (int ki = 0; ki < 8; ki++) {
            acc0 = __builtin_amdgcn_mfma_f32_16x16x32_bf16(afr[ki], bfrag[0][ki], acc0, 0, 0, 0);
            acc1 = __builtin_amdgcn_mfma_f32_16x16x32_bf16(afr[ki], bfrag[1][ki], acc1, 0, 0, 0);
        }

        // prefetch x_{t+1} while MFMAs drain
        float xn[2][4] = {{0.f,0.f,0.f,0.f},{0.f,0.f,0.f,0.f}};
        if (t + 1 < SEQT) {
#pragma unroll
            for (int nt = 0; nt < 2; nt++) {
                int n = w * 32 + nt * 16 + lr;
#pragma unroll
                for (int r = 0; r < 4; r++)
                    xn[nt][r] = Wih[(size_t)ids[(t + 1) * 16 + lh * 4 + r] * HID + n] + bb[nt];
            }
        }

        __syncthreads();   // all reads of h_{t-1} done before overwrite

        // C/D layout: col = lane&15 (n), row = (lane>>4)*4 + reg (m)
#pragma unroll
        for (int nt = 0; nt < 2; nt++) {
            int n = w * 32 + nt * 16 + lr;
#pragma unroll
            for (int r = 0; r < 4; r++) {
                int m = lh * 4 + r;
                float v = (nt ? acc1[r] : acc0[r]) + xv[nt][r];
                short hb = f2bs(tanh_fast(v));
                hbuf[m][n] = hb;
                hs[((size_t)m * SEQT + t) * HID + n] = *reinterpret_cast<__hip_bfloat16*>(&hb);
            }
        }
#pragma unroll
        for (int nt = 0; nt < 2; nt++)
#pragma unroll
            for (int r = 0; r < 4; r++) xv[nt][r] = xn[nt][r];
        __syncthreads();   // h_t visible before next step's A-frag reads
    }
}

// ---------------------------------------------------------------------------
// K2: target logit: TL[r] = dot(hs[r], Wfc[tgt[r]]) + bfc[tgt[r]]   (fp32 W)
// ---------------------------------------------------------------------------
__global__ __launch_bounds__(256) void tlogit_kernel(
    const __hip_bfloat16* __restrict__ hs,
    const float* __restrict__ Wfc,
    const float* __restrict__ bfc,
    const int* __restrict__ targets,
    float* __restrict__ TL)
{
    int w = threadIdx.x >> 6, l = threadIdx.x & 63;
    int r = blockIdx.x * 4 + w;
    int tg = targets[r];
    const __hip_bfloat16* hrow = hs + (size_t)r * HID + l * 4;
    const float4 wv = *(const float4*)(Wfc + (size_t)tg * HID + l * 4);
    float s = __bfloat162float(hrow[0]) * wv.x + __bfloat162float(hrow[1]) * wv.y
            + __bfloat162float(hrow[2]) * wv.z + __bfloat162float(hrow[3]) * wv.w;
#pragma unroll
    for (int m = 1; m < 64; m <<= 1) s += __shfl_xor(s, m, 64);
    if (l == 0) TL[r] = s + bfc[tg];
}

// ---------------------------------------------------------------------------
// K3: fused FC GEMM + exp-rowsum. Tile 128(M) x 128(N vocab), K=256.
// A = hs (bf16); B = Wfc (fp32, converted to bf16 during register staging).
// |logit| <= ~16.1 so fp32 exp needs no max subtraction.
// LDS k-slab-major: slot(slab,row) holds 8 bf16 -> staging stores and
// fragment ds_read_b128 are both contiguous.
// ---------------------------------------------------------------------------
__global__ __launch_bounds__(256, 2) void fc_kernel(
    const __hip_bfloat16* __restrict__ hs,
    const float* __restrict__ Wfc,
    const float* __restrict__ bfc,
    float* __restrict__ S)
{
    __shared__ short As[4 * 128 * 8];
    __shared__ short Bs[4 * 128 * 8];
    const int tid = threadIdx.x;
    const int l = tid & 63, w = tid >> 6;
    const int lr = l & 15, lh = l >> 4;
    const int m0 = blockIdx.x * 128;
    const int n0 = blockIdx.y * 128;
    const int wm = (w >> 1) * 64, wn = (w & 1) * 64;
    const int srow = tid & 127, ssl = tid >> 7;

    f32x4_t acc[4][4];
    const f32x4_t z = {0.f, 0.f, 0.f, 0.f};
#pragma unroll
    for (int i = 0; i < 4; i++)
#pragma unroll
        for (int j = 0; j < 4; j++) acc[i][j] = z;

    const __hip_bfloat16* gA = hs + (size_t)(m0 + srow) * HID + ssl * 8;
    const float*          gB = Wfc + (size_t)(n0 + srow) * HID + ssl * 8;
    bf16x8_t* sA0 = (bf16x8_t*)(As + tid * 8);
    bf16x8_t* sA1 = (bf16x8_t*)(As + (tid + 256) * 8);
    bf16x8_t* sB0 = (bf16x8_t*)(Bs + tid * 8);
    bf16x8_t* sB1 = (bf16x8_t*)(Bs + (tid + 256) * 8);

    for (int ks = 0; ks < 8; ks++) {
        int k0 = ks * 32;
        bf16x8_t va0 = *(const bf16x8_t*)(gA + k0);
        bf16x8_t va1 = *(const bf16x8_t*)(gA + k0 + 16);
        const float4* pb0 = (const float4*)(gB + k0);
        const float4* pb1 = (const float4*)(gB + k0 + 16);
        bf16x8_t vb0 = cvt8(pb0[0], pb0[1]);
        bf16x8_t vb1 = cvt8(pb1[0], pb1[1]);
        __syncthreads();          // prev iter's fragment reads done
        *sA0 = va0; *sA1 = va1; *sB0 = vb0; *sB1 = vb1;
        __syncthreads();          // staging visible

        bf16x8_t a[4], b[4];
#pragma unroll
        for (int mt = 0; mt < 4; mt++)
            a[mt] = *(const bf16x8_t*)(As + (lh * 128 + wm + mt * 16 + lr) * 8);
#pragma unroll
        for (int nt = 0; nt < 4; nt++)
            b[nt] = *(const bf16x8_t*)(Bs + (lh * 128 + wn + nt * 16 + lr) * 8);
#pragma unroll
        for (int mt = 0; mt < 4; mt++)
#pragma unroll
            for (int nt = 0; nt < 4; nt++)
                acc[mt][nt] = __builtin_amdgcn_mfma_f32_16x16x32_bf16(a[mt], b[nt], acc[mt][nt], 0, 0, 0);
    }

    // epilogue: bias + exp + per-row partial sums (16 rows/lane, 4 cols each)
    float rsum[16];
#pragma unroll
    for (int i = 0; i < 16; i++) rsum[i] = 0.f;
#pragma unroll
    for (int nt = 0; nt < 4; nt++) {
        int n = n0 + wn + nt * 16 + lr;
        float bias = bfc[n];
#pragma unroll
        for (int mt = 0; mt < 4; mt++)
#pragma unroll
            for (int r = 0; r < 4; r++)
                rsum[mt * 4 + r] += __expf(acc[mt][nt][r] + bias);
    }
    // butterfly over the 16 column-lanes (lane bits 0..3)
#pragma unroll
    for (int m = 1; m < 16; m <<= 1)
#pragma unroll
        for (int i = 0; i < 16; i++) rsum[i] += __shfl_xor(rsum[i], m, 64);
    if (lr == 0) {
#pragma unroll
        for (int i = 0; i < 16; i++) {
            int row = m0 + wm + (i >> 2) * 16 + lh * 4 + (i & 3);
            atomicAdd(&S[row], rsum[i]);
        }
    }
}

// ---------------------------------------------------------------------------
// K4: loss = mean_r( log(S[r]) - TL[r] ), fp32 scalar out
// ---------------------------------------------------------------------------
__global__ __launch_bounds__(256) void loss_kernel(
    const float* __restrict__ S,
    const float* __restrict__ TL,
    float* __restrict__ out)
{
    int tid = threadIdx.x;
    float p = 0.f;
    for (int i = tid; i < ROWS; i += 256) p += __logf(S[i]) - TL[i];
#pragma unroll
    for (int m = 1; m < 64; m <<= 1) p += __shfl_xor(p, m, 64);
    __shared__ float red[4];
    if ((tid & 63) == 0) red[tid >> 6] = p;
    __syncthreads();
    if (tid == 0)
        out[0] = (red[0] + red[1] + red[2] + red[3]) / (float)ROWS;
}

extern "C" void kernel_launch(void* const* d_in, const int* in_sizes, int n_in,
                              void* d_out, int out_size, void* d_ws, size_t ws_size,
                              hipStream_t stream)
{
    (void)in_sizes; (void)n_in; (void)out_size; (void)ws_size;
    const int*   inputs  = (const int*)d_in[0];
    const int*   targets = (const int*)d_in[1];
    const float* Wih = (const float*)d_in[2];
    const float* bih = (const float*)d_in[3];
    const float* Whh = (const float*)d_in[4];
    const float* bhh = (const float*)d_in[5];
    const float* Wfc = (const float*)d_in[6];
    const float* bfc = (const float*)d_in[7];

    float* S  = (float*)d_ws;                     // 4096 f32 (sum of exps)
    float* TL = S + ROWS;                         // 4096 f32 (target logits)
    __hip_bfloat16* hs = (__hip_bfloat16*)(TL + ROWS);  // [B][T][H] bf16, 2 MB

    zinit_kernel<<<ROWS / 256, 256, 0, stream>>>(S);
    rnn_kernel<<<1, 512, 0, stream>>>(inputs, Wih, bih, bhh, Whh, hs);
    tlogit_kernel<<<ROWS / 4, 256, 0, stream>>>(hs, Wfc, bfc, targets, TL);
    dim3 g3(32, 250);
    fc_kernel<<<g3, 256, 0, stream>>>(hs, Wfc, bfc, S);
    loss_kernel<<<1, 256, 0, stream>>>(S, TL, (float*)d_out);
}

// Round 4
// 562.126 us; speedup vs baseline: 1.2186x; 1.2186x over previous
//
#include <hip/hip_runtime.h>
#include <hip/hip_bf16.h>
#include <stdint.h>

#define VOCAB 32000
#define HID   256
#define BATCH 16
#define SEQT  256
#define ROWS  (BATCH*SEQT)   // 4096

typedef __attribute__((ext_vector_type(8))) short bf16x8_t;
typedef __attribute__((ext_vector_type(4))) float f32x4_t;

__device__ __forceinline__ short f2bs(float x) {
    __hip_bfloat16 h = __float2bfloat16(x);
    return *reinterpret_cast<short*>(&h);
}
__device__ __forceinline__ bf16x8_t cvt8(float4 a, float4 b) {
    union { short s[8]; bf16x8_t v; } u;
    u.s[0] = f2bs(a.x); u.s[1] = f2bs(a.y); u.s[2] = f2bs(a.z); u.s[3] = f2bs(a.w);
    u.s[4] = f2bs(b.x); u.s[5] = f2bs(b.y); u.s[6] = f2bs(b.z); u.s[7] = f2bs(b.w);
    return u.v;
}
__device__ __forceinline__ float tanh_fast(float x) {
    float e = __expf(2.0f * x);
    return 1.0f - 2.0f / (e + 1.0f);
}
// workgroup barrier that drains ONLY lgkmcnt (LDS); global loads/stores stay
// in flight (compiler inserts vmcnt waits before uses of loaded values).
__device__ __forceinline__ void barrier_lds() {
    asm volatile("s_waitcnt lgkmcnt(0)\n\ts_barrier" ::: "memory");
}

// ---------------------------------------------------------------------------
// K0: zero S[4096]
// ---------------------------------------------------------------------------
__global__ __launch_bounds__(256) void zinit_kernel(float* __restrict__ S) {
    S[blockIdx.x * 256 + threadIdx.x] = 0.0f;
}

// ---------------------------------------------------------------------------
// K1: xp[t][b][h] = Wih[inputs[b][t]][h] + bih[h] + bhh[h]   (fp32, parallel)
// ---------------------------------------------------------------------------
__global__ __launch_bounds__(256) void xproj_kernel(
    const int* __restrict__ inputs,
    const float* __restrict__ Wih,
    const float* __restrict__ bih,
    const float* __restrict__ bhh,
    float* __restrict__ xp)
{
    int idx = blockIdx.x * 256 + threadIdx.x;  // (t*16+b)*256 + h
    int h  = idx & 255;
    int tb = idx >> 8;
    int b  = tb & 15;
    int t  = tb >> 4;
    int id = inputs[b * SEQT + t];
    xp[idx] = Wih[(size_t)id * HID + h] + bih[h] + bhh[h];
}

// ---------------------------------------------------------------------------
// K2: RNN recurrence. One block, 512 threads (8 waves), M=16, N=K=256.
// Whh bf16 B-fragments in registers; h double-buffered in LDS -> ONE light
// barrier per step (no vmcnt drain: xp prefetch + hs stores stay in flight).
// h_t = tanh(xp_t + h_{t-1} @ Whh^T) -> hs[t][b][h] (bf16)
// ---------------------------------------------------------------------------
__global__ __launch_bounds__(512, 1) void rnn_kernel(
    const float* __restrict__ xp,          // [T][B][H] fp32 (biases folded)
    const float* __restrict__ Whh,
    __hip_bfloat16* __restrict__ hs)       // [T][B][H] bf16
{
    __shared__ short hbuf[2][16][264];     // +8 pad
    const int tid = threadIdx.x;
    const int l = tid & 63, w = tid >> 6;
    const int lr = l & 15, lh = l >> 4;

    // B fragments: B[k][n] = Whh[n][k]; lane n = w*32+nt*16+lr, k = ki*32+lh*8+j
    bf16x8_t bfrag[2][8];
#pragma unroll
    for (int nt = 0; nt < 2; nt++) {
        int n = w * 32 + nt * 16 + lr;
#pragma unroll
        for (int ki = 0; ki < 8; ki++) {
            const float4* p = (const float4*)(Whh + n * HID + ki * 32 + lh * 8);
            bfrag[nt][ki] = cvt8(p[0], p[1]);
        }
    }
    for (int i = tid; i < 16 * 264; i += 512) ((short*)hbuf[0])[i] = 0;
    __syncthreads();

    // per-lane output coords: rows m = lh*4+r, cols n = w*32+nt*16+lr
    // prefetch x for t=0
    float xv[2][4];
#pragma unroll
    for (int nt = 0; nt < 2; nt++) {
        int n = w * 32 + nt * 16 + lr;
#pragma unroll
        for (int r = 0; r < 4; r++)
            xv[nt][r] = xp[(lh * 4 + r) * HID + n];
    }

    int cur = 0;
    for (int t = 0; t < SEQT; t++) {
        // prefetch x_{t+1} early: latency overlaps this step's MFMA phase
        float xn[2][4] = {{0.f,0.f,0.f,0.f},{0.f,0.f,0.f,0.f}};
        if (t + 1 < SEQT) {
            const float* xbase = xp + (size_t)(t + 1) * BATCH * HID;
#pragma unroll
            for (int nt = 0; nt < 2; nt++) {
                int n = w * 32 + nt * 16 + lr;
#pragma unroll
                for (int r = 0; r < 4; r++)
                    xn[nt][r] = xbase[(lh * 4 + r) * HID + n];
            }
        }

        // A fragments from LDS: A[m=lr][k=ki*32+lh*8+j]
        bf16x8_t afr[8];
#pragma unroll
        for (int ki = 0; ki < 8; ki++)
            afr[ki] = *(const bf16x8_t*)(&hbuf[cur][lr][ki * 32 + lh * 8]);

        f32x4_t acc0 = {0.f, 0.f, 0.f, 0.f}, acc1 = {0.f, 0.f, 0.f, 0.f};
#pragma unroll
        for (int ki = 0; ki < 8; ki++) {
            acc0 = __builtin_amdgcn_mfma_f32_16x16x32_bf16(afr[ki], bfrag[0][ki], acc0, 0, 0, 0);
            acc1 = __builtin_amdgcn_mfma_f32_16x16x32_bf16(afr[ki], bfrag[1][ki], acc1, 0, 0, 0);
        }

        // C/D layout: col = lane&15 (n), row = (lane>>4)*4 + reg (m)
        __hip_bfloat16* hrow = hs + (size_t)t * BATCH * HID;
#pragma unroll
        for (int nt = 0; nt < 2; nt++) {
            int n = w * 32 + nt * 16 + lr;
#pragma unroll
            for (int r = 0; r < 4; r++) {
                int m = lh * 4 + r;
                float v = (nt ? acc1[r] : acc0[r]) + xv[nt][r];
                short hb = f2bs(tanh_fast(v));
                hbuf[cur ^ 1][m][n] = hb;
                hrow[m * HID + n] = *reinterpret_cast<__hip_bfloat16*>(&hb);
            }
        }
#pragma unroll
        for (int nt = 0; nt < 2; nt++)
#pragma unroll
            for (int r = 0; r < 4; r++) xv[nt][r] = xn[nt][r];
        cur ^= 1;
        barrier_lds();   // single barrier/step; ds ops drained, vmem in flight
    }
}

// ---------------------------------------------------------------------------
// K3: target logit: TL[r] = dot(hs[r], Wfc[tgt]) + bfc[tgt]; row r = t*16+b
// ---------------------------------------------------------------------------
__global__ __launch_bounds__(256) void tlogit_kernel(
    const __hip_bfloat16* __restrict__ hs,
    const float* __restrict__ Wfc,
    const float* __restrict__ bfc,
    const int* __restrict__ targets,
    float* __restrict__ TL)
{
    int w = threadIdx.x >> 6, l = threadIdx.x & 63;
    int r = blockIdx.x * 4 + w;
    int b = r & 15, t = r >> 4;
    int tg = targets[b * SEQT + t];
    const __hip_bfloat16* hrow = hs + (size_t)r * HID + l * 4;
    const float4 wv = *(const float4*)(Wfc + (size_t)tg * HID + l * 4);
    float s = __bfloat162float(hrow[0]) * wv.x + __bfloat162float(hrow[1]) * wv.y
            + __bfloat162float(hrow[2]) * wv.z + __bfloat162float(hrow[3]) * wv.w;
#pragma unroll
    for (int m = 1; m < 64; m <<= 1) s += __shfl_xor(s, m, 64);
    if (l == 0) TL[r] = s + bfc[tg];
}

// ---------------------------------------------------------------------------
// K4: fused FC GEMM + exp-rowsum. Tile 128(M rows=(t,b)) x 128(N vocab), K=256.
// Software-pipelined register staging: next k-slab's global loads issue right
// after the staging barrier, overlapping the MFMA phase. Light barriers only.
// |logit| <= ~16.1 so fp32 exp needs no max subtraction.
// ---------------------------------------------------------------------------
__global__ __launch_bounds__(256) void fc_kernel(
    const __hip_bfloat16* __restrict__ hs,
    const float* __restrict__ Wfc,
    const float* __restrict__ bfc,
    float* __restrict__ S)
{
    __shared__ short As[4 * 128 * 8];
    __shared__ short Bs[4 * 128 * 8];
    const int tid = threadIdx.x;
    const int l = tid & 63, w = tid >> 6;
    const int lr = l & 15, lh = l >> 4;
    const int m0 = blockIdx.x * 128;
    const int n0 = blockIdx.y * 128;
    const int wm = (w >> 1) * 64, wn = (w & 1) * 64;
    const int srow = tid & 127, ssl = tid >> 7;

    f32x4_t acc[4][4];
    const f32x4_t z = {0.f, 0.f, 0.f, 0.f};
#pragma unroll
    for (int i = 0; i < 4; i++)
#pragma unroll
        for (int j = 0; j < 4; j++) acc[i][j] = z;

    const __hip_bfloat16* gA = hs + (size_t)(m0 + srow) * HID + ssl * 8;
    const float*          gB = Wfc + (size_t)(n0 + srow) * HID + ssl * 8;
    bf16x8_t* sA0 = (bf16x8_t*)(As + tid * 8);
    bf16x8_t* sA1 = (bf16x8_t*)(As + (tid + 256) * 8);
    bf16x8_t* sB0 = (bf16x8_t*)(Bs + tid * 8);
    bf16x8_t* sB1 = (bf16x8_t*)(Bs + (tid + 256) * 8);

    // preload k-slab 0
    bf16x8_t ca0 = *(const bf16x8_t*)(gA);
    bf16x8_t ca1 = *(const bf16x8_t*)(gA + 16);
    float4 cb0 = ((const float4*)(gB))[0],      cb1 = ((const float4*)(gB))[1];
    float4 cb2 = ((const float4*)(gB + 16))[0], cb3 = ((const float4*)(gB + 16))[1];

    for (int ks = 0; ks < 8; ks++) {
        barrier_lds();            // prev iter's fragment reads done
        *sA0 = ca0; *sA1 = ca1;
        *sB0 = cvt8(cb0, cb1); *sB1 = cvt8(cb2, cb3);
        barrier_lds();            // staging visible

        if (ks < 7) {             // prefetch next slab; overlaps MFMA below
            int k1 = (ks + 1) * 32;
            ca0 = *(const bf16x8_t*)(gA + k1);
            ca1 = *(const bf16x8_t*)(gA + k1 + 16);
            cb0 = ((const float4*)(gB + k1))[0];      cb1 = ((const float4*)(gB + k1))[1];
            cb2 = ((const float4*)(gB + k1 + 16))[0]; cb3 = ((const float4*)(gB + k1 + 16))[1];
        }

        bf16x8_t a[4], b[4];
#pragma unroll
        for (int mt = 0; mt < 4; mt++)
            a[mt] = *(const bf16x8_t*)(As + (lh * 128 + wm + mt * 16 + lr) * 8);
#pragma unroll
        for (int nt = 0; nt < 4; nt++)
            b[nt] = *(const bf16x8_t*)(Bs + (lh * 128 + wn + nt * 16 + lr) * 8);
#pragma unroll
        for (int mt = 0; mt < 4; mt++)
#pragma unroll
            for (int nt = 0; nt < 4; nt++)
                acc[mt][nt] = __builtin_amdgcn_mfma_f32_16x16x32_bf16(a[mt], b[nt], acc[mt][nt], 0, 0, 0);
    }

    // epilogue: bias + exp + per-row partials (16 rows/lane over 4 cols)
    float rsum[16];
#pragma unroll
    for (int i = 0; i < 16; i++) rsum[i] = 0.f;
#pragma unroll
    for (int nt = 0; nt < 4; nt++) {
        int n = n0 + wn + nt * 16 + lr;
        float bias = bfc[n];
#pragma unroll
        for (int mt = 0; mt < 4; mt++)
#pragma unroll
            for (int r = 0; r < 4; r++)
                rsum[mt * 4 + r] += __expf(acc[mt][nt][r] + bias);
    }
#pragma unroll
    for (int m = 1; m < 16; m <<= 1)
#pragma unroll
        for (int i = 0; i < 16; i++) rsum[i] += __shfl_xor(rsum[i], m, 64);
    if (lr == 0) {
#pragma unroll
        for (int i = 0; i < 16; i++) {
            int row = m0 + wm + (i >> 2) * 16 + lh * 4 + (i & 3);
            atomicAdd(&S[row], rsum[i]);
        }
    }
}

// ---------------------------------------------------------------------------
// K5: loss = mean_r( log(S[r]) - TL[r] ), fp32 scalar out
// ---------------------------------------------------------------------------
__global__ __launch_bounds__(256) void loss_kernel(
    const float* __restrict__ S,
    const float* __restrict__ TL,
    float* __restrict__ out)
{
    int tid = threadIdx.x;
    float p = 0.f;
    for (int i = tid; i < ROWS; i += 256) p += __logf(S[i]) - TL[i];
#pragma unroll
    for (int m = 1; m < 64; m <<= 1) p += __shfl_xor(p, m, 64);
    __shared__ float red[4];
    if ((tid & 63) == 0) red[tid >> 6] = p;
    __syncthreads();
    if (tid == 0)
        out[0] = (red[0] + red[1] + red[2] + red[3]) / (float)ROWS;
}

extern "C" void kernel_launch(void* const* d_in, const int* in_sizes, int n_in,
                              void* d_out, int out_size, void* d_ws, size_t ws_size,
                              hipStream_t stream)
{
    (void)in_sizes; (void)n_in; (void)out_size; (void)ws_size;
    const int*   inputs  = (const int*)d_in[0];
    const int*   targets = (const int*)d_in[1];
    const float* Wih = (const float*)d_in[2];
    const float* bih = (const float*)d_in[3];
    const float* Whh = (const float*)d_in[4];
    const float* bhh = (const float*)d_in[5];
    const float* Wfc = (const float*)d_in[6];
    const float* bfc = (const float*)d_in[7];

    float* S  = (float*)d_ws;                           // 4096 f32
    float* TL = S + ROWS;                               // 4096 f32
    float* xp = TL + ROWS;                              // [T][B][H] fp32, 4 MB
    __hip_bfloat16* hs = (__hip_bfloat16*)(xp + (size_t)SEQT * BATCH * HID); // 2 MB

    zinit_kernel<<<ROWS / 256, 256, 0, stream>>>(S);
    xproj_kernel<<<(SEQT * BATCH * HID) / 256, 256, 0, stream>>>(inputs, Wih, bih, bhh, xp);
    rnn_kernel<<<1, 512, 0, stream>>>(xp, Whh, hs);
    tlogit_kernel<<<ROWS / 4, 256, 0, stream>>>(hs, Wfc, bfc, targets, TL);
    dim3 g3(32, 250);
    fc_kernel<<<g3, 256, 0, stream>>>(hs, Wfc, bfc, S);
    loss_kernel<<<1, 256, 0, stream>>>(S, TL, (float*)d_out);
}

// Round 5
// 451.085 us; speedup vs baseline: 1.5186x; 1.2462x over previous
//
#include <hip/hip_runtime.h>
#include <hip/hip_bf16.h>
#include <stdint.h>

#define VOCAB 32000
#define HID   256
#define BATCH 16
#define SEQT  256
#define ROWS  (BATCH*SEQT)   // 4096

typedef __attribute__((ext_vector_type(8))) short bf16x8_t;
typedef __attribute__((ext_vector_type(4))) float f32x4_t;

__device__ __forceinline__ short f2bs(float x) {
    __hip_bfloat16 h = __float2bfloat16(x);
    return *reinterpret_cast<short*>(&h);
}
__device__ __forceinline__ bf16x8_t cvt8(float4 a, float4 b) {
    union { short s[8]; bf16x8_t v; } u;
    u.s[0] = f2bs(a.x); u.s[1] = f2bs(a.y); u.s[2] = f2bs(a.z); u.s[3] = f2bs(a.w);
    u.s[4] = f2bs(b.x); u.s[5] = f2bs(b.y); u.s[6] = f2bs(b.z); u.s[7] = f2bs(b.w);
    return u.v;
}
// workgroup barrier draining ONLY lgkmcnt; vmem stays in flight
__device__ __forceinline__ void barrier_lds() {
    asm volatile("s_waitcnt lgkmcnt(0)\n\ts_barrier" ::: "memory");
}
// tanh via Lambert CF5: x(x^4+105x^2+945)/(15x^4+420x^2+945), |err|<1.2e-3
// for |x|<3.5 (typical |x|<2 here); clamp handles the tails exactly.
__device__ __forceinline__ float tanh_cf(float x) {
    float x2 = x * x;
    float nm = x * fmaf(x2, x2 + 105.f, 945.f);
    float dn = fmaf(x2, fmaf(x2, 15.f, 420.f), 945.f);
    float h = nm * __builtin_amdgcn_rcpf(dn);
    return fminf(fmaxf(h, -1.f), 1.f);
}
// manual round-to-nearest-even fp32 -> bf16 bits (inputs always finite here)
__device__ __forceinline__ short rne_bf16(float x) {
    uint32_t u = __float_as_uint(x);
    uint32_t r = (u + 0x7FFFu + ((u >> 16) & 1u)) >> 16;
    return (short)r;
}

// ---------------------------------------------------------------------------
// K1: xp[t][b][h] = Wih[inputs[b][t]][h]+bih[h]+bhh[h]; also zeroes S and
// (optionally) converts Wfc fp32 -> bf16 into Wfcb. 4096 blocks x 256.
// ---------------------------------------------------------------------------
__global__ __launch_bounds__(256) void xproj_kernel(
    const int* __restrict__ inputs,
    const float* __restrict__ Wih,
    const float* __restrict__ bih,
    const float* __restrict__ bhh,
    const float* __restrict__ Wfc,
    float* __restrict__ xp,
    float* __restrict__ S,
    __hip_bfloat16* __restrict__ Wfcb,
    int do_cvt)
{
    int idx = blockIdx.x * 256 + threadIdx.x;  // (t*16+b)*256 + h
    int h  = idx & 255;
    int tb = idx >> 8;
    int b  = tb & 15;
    int t  = tb >> 4;
    int id = inputs[b * SEQT + t];
    xp[idx] = Wih[(size_t)id * HID + h] + bih[h] + bhh[h];
    if (idx < ROWS) S[idx] = 0.0f;
    if (do_cvt && idx < (VOCAB * HID / 8)) {
        const float4* p = (const float4*)(Wfc + (size_t)idx * 8);
        *(bf16x8_t*)((short*)Wfcb + (size_t)idx * 8) = cvt8(p[0], p[1]);
    }
}

// ---------------------------------------------------------------------------
// K2: RNN recurrence. One block, 512 threads (8 waves), M=16, N=K=256.
// Whh bf16 B-fragments in registers; h double-buffered in LDS; ONE lgkm-only
// barrier/step. h_{t-1} copied LDS->global as b128 during step t (pipelined).
// ---------------------------------------------------------------------------
__global__ __launch_bounds__(512, 1) void rnn_kernel(
    const float* __restrict__ xp,          // [T][B][H] fp32 (biases folded)
    const float* __restrict__ Whh,
    __hip_bfloat16* __restrict__ hs)       // [T][B][H] bf16
{
    __shared__ short hbuf[2][16][264];     // +8 pad
    const int tid = threadIdx.x;
    const int l = tid & 63, w = tid >> 6;
    const int lr = l & 15, lh = l >> 4;
    const int cm = tid >> 5;               // copy: row 0..15
    const int cc = (tid & 31) * 8;         // copy: col (x8 shorts)

    // B fragments: B[k][n] = Whh[n][k]; lane n = w*32+nt*16+lr, k=ki*32+lh*8+j
    bf16x8_t bfrag[2][8];
#pragma unroll
    for (int nt = 0; nt < 2; nt++) {
        int n = w * 32 + nt * 16 + lr;
#pragma unroll
        for (int ki = 0; ki < 8; ki++) {
            const float4* p = (const float4*)(Whh + n * HID + ki * 32 + lh * 8);
            bfrag[nt][ki] = cvt8(p[0], p[1]);
        }
    }
    for (int i = tid; i < 16 * 264; i += 512) ((short*)hbuf[0])[i] = 0;
    __syncthreads();

    // prefetch x for t=0: rows m=lh*4+r, cols n=w*32+nt*16+lr
    float xv[2][4];
#pragma unroll
    for (int nt = 0; nt < 2; nt++) {
        int n = w * 32 + nt * 16 + lr;
#pragma unroll
        for (int r = 0; r < 4; r++)
            xv[nt][r] = xp[(lh * 4 + r) * HID + n];
    }

    int cur = 0;
    for (int t = 0; t < SEQT; t++) {
        // pipelined copy of h_{t-1} (in hbuf[cur]) to global hs
        if (t > 0) {
            bf16x8_t hv = *(const bf16x8_t*)(&hbuf[cur][cm][cc]);
            *(bf16x8_t*)((short*)hs + (size_t)(t - 1) * BATCH * HID + cm * HID + cc) = hv;
        }

        // A fragments: A[m=lr][k=ki*32+lh*8+j]
        bf16x8_t afr[8];
#pragma unroll
        for (int ki = 0; ki < 8; ki++)
            afr[ki] = *(const bf16x8_t*)(&hbuf[cur][lr][ki * 32 + lh * 8]);

        // two 4-deep chains per n-tile (halved dependent-MFMA latency)
        f32x4_t a0a = {0,0,0,0}, a0b = {0,0,0,0}, a1a = {0,0,0,0}, a1b = {0,0,0,0};
#pragma unroll
        for (int ki = 0; ki < 4; ki++) {
            a0a = __builtin_amdgcn_mfma_f32_16x16x32_bf16(afr[ki],     bfrag[0][ki],     a0a, 0, 0, 0);
            a0b = __builtin_amdgcn_mfma_f32_16x16x32_bf16(afr[ki + 4], bfrag[0][ki + 4], a0b, 0, 0, 0);
            a1a = __builtin_amdgcn_mfma_f32_16x16x32_bf16(afr[ki],     bfrag[1][ki],     a1a, 0, 0, 0);
            a1b = __builtin_amdgcn_mfma_f32_16x16x32_bf16(afr[ki + 4], bfrag[1][ki + 4], a1b, 0, 0, 0);
        }

        // prefetch x_{t+1}; latency hidden behind MFMA + epilogue
        float xn[2][4] = {{0,0,0,0},{0,0,0,0}};
        if (t + 1 < SEQT) {
            const float* xbase = xp + (size_t)(t + 1) * BATCH * HID;
#pragma unroll
            for (int nt = 0; nt < 2; nt++) {
                int n = w * 32 + nt * 16 + lr;
#pragma unroll
                for (int r = 0; r < 4; r++)
                    xn[nt][r] = xbase[(lh * 4 + r) * HID + n];
            }
        }

        // C/D: col = lane&15 (n), row = (lane>>4)*4 + reg (m)
#pragma unroll
        for (int nt = 0; nt < 2; nt++) {
            int n = w * 32 + nt * 16 + lr;
#pragma unroll
            for (int r = 0; r < 4; r++) {
                float v = (nt ? (a1a[r] + a1b[r]) : (a0a[r] + a0b[r])) + xv[nt][r];
                hbuf[cur ^ 1][lh * 4 + r][n] = rne_bf16(tanh_cf(v));
            }
        }
#pragma unroll
        for (int nt = 0; nt < 2; nt++)
#pragma unroll
            for (int r = 0; r < 4; r++) xv[nt][r] = xn[nt][r];
        cur ^= 1;
        barrier_lds();
    }
    // final copy: h_{T-1}
    bf16x8_t hv = *(const bf16x8_t*)(&hbuf[cur][cm][cc]);
    *(bf16x8_t*)((short*)hs + (size_t)(SEQT - 1) * BATCH * HID + cm * HID + cc) = hv;
}

// ---------------------------------------------------------------------------
// K3: fused FC GEMM + exp-rowsum + target-logit extraction.
// Tile 128m x 128n, K=256 in 8 slabs of 32. Double-buffered LDS, ONE
// lgkm-only barrier per slab, 2-slab register prefetch. XCD-swizzled grid:
// all 32 m-blocks of an n-panel land on one XCD -> B tile hits its L2.
// BF16B: B pre-converted to bf16 (else fp32 + inline cvt).
// ---------------------------------------------------------------------------
template <bool BF16B>
__global__ __launch_bounds__(256) void fc_kernel(
    const __hip_bfloat16* __restrict__ hs,
    const void* __restrict__ WfcP,
    const float* __restrict__ bfc,
    const int* __restrict__ targets,
    float* __restrict__ S,
    float* __restrict__ TL)
{
    __shared__ short As[2][4 * 128 * 8];
    __shared__ short Bs[2][4 * 128 * 8];
    __shared__ int tgt[128];

    const int bid = blockIdx.x;
    const int xcd = bid & 7;
    const int j   = bid >> 3;
    const int m_id = j & 31;
    const int n_id = (j >> 5) * 8 + xcd;
    if (n_id >= VOCAB / 128) return;
    const int m0 = m_id * 128, n0 = n_id * 128;

    const int tid = threadIdx.x;
    const int l = tid & 63, w = tid >> 6;
    const int lr = l & 15, lh = l >> 4;
    const int wm = (w >> 1) * 64, wn = (w & 1) * 64;
    const int row = tid & 127, sub = tid >> 7;   // 2 slots: (sub,row),(sub+2,row)

    if (tid < 128) {
        int r = m0 + tid;                        // r = t*16+b
        tgt[tid] = targets[((r & 15) << 8) | (r >> 4)];
    }

    f32x4_t acc[4][4];
    const f32x4_t z = {0.f, 0.f, 0.f, 0.f};
#pragma unroll
    for (int i = 0; i < 4; i++)
#pragma unroll
        for (int jj = 0; jj < 4; jj++) acc[i][jj] = z;

    const __hip_bfloat16* gA = hs + (size_t)(m0 + row) * HID + sub * 8;
    const __hip_bfloat16* gBb = (const __hip_bfloat16*)WfcP + (size_t)(n0 + row) * HID + sub * 8;
    const float*          gBf = (const float*)WfcP + (size_t)(n0 + row) * HID + sub * 8;

    bf16x8_t rA0, rA1, rB0, rB1;
    float4 rf0a, rf0b, rf1a, rf1b;

    // slab 0 -> LDS[0]
    {
        rA0 = *(const bf16x8_t*)(gA);
        rA1 = *(const bf16x8_t*)(gA + 16);
        *(bf16x8_t*)&As[0][(sub * 128 + row) * 8] = rA0;
        *(bf16x8_t*)&As[0][((sub + 2) * 128 + row) * 8] = rA1;
        if (BF16B) {
            rB0 = *(const bf16x8_t*)(gBb);
            rB1 = *(const bf16x8_t*)(gBb + 16);
            *(bf16x8_t*)&Bs[0][(sub * 128 + row) * 8] = rB0;
            *(bf16x8_t*)&Bs[0][((sub + 2) * 128 + row) * 8] = rB1;
        } else {
            const float4* p0 = (const float4*)(gBf);
            const float4* p1 = (const float4*)(gBf + 16);
            *(bf16x8_t*)&Bs[0][(sub * 128 + row) * 8] = cvt8(p0[0], p0[1]);
            *(bf16x8_t*)&Bs[0][((sub + 2) * 128 + row) * 8] = cvt8(p1[0], p1[1]);
        }
    }
    // prefetch slab 1
    {
        rA0 = *(const bf16x8_t*)(gA + 32);
        rA1 = *(const bf16x8_t*)(gA + 48);
        if (BF16B) {
            rB0 = *(const bf16x8_t*)(gBb + 32);
            rB1 = *(const bf16x8_t*)(gBb + 48);
        } else {
            rf0a = ((const float4*)(gBf + 32))[0]; rf0b = ((const float4*)(gBf + 32))[1];
            rf1a = ((const float4*)(gBf + 48))[0]; rf1b = ((const float4*)(gBf + 48))[1];
        }
    }
    __syncthreads();

    for (int s = 0; s < 8; s++) {
        const int buf = s & 1;
        bf16x8_t a[4], b[4];
#pragma unroll
        for (int mt = 0; mt < 4; mt++)
            a[mt] = *(const bf16x8_t*)&As[buf][(lh * 128 + wm + mt * 16 + lr) * 8];
#pragma unroll
        for (int nt = 0; nt < 4; nt++)
            b[nt] = *(const bf16x8_t*)&Bs[buf][(lh * 128 + wn + nt * 16 + lr) * 8];

        if (s + 1 < 8) {   // stage prefetched regs into the other buffer
            *(bf16x8_t*)&As[buf ^ 1][(sub * 128 + row) * 8] = rA0;
            *(bf16x8_t*)&As[buf ^ 1][((sub + 2) * 128 + row) * 8] = rA1;
            if (BF16B) {
                *(bf16x8_t*)&Bs[buf ^ 1][(sub * 128 + row) * 8] = rB0;
                *(bf16x8_t*)&Bs[buf ^ 1][((sub + 2) * 128 + row) * 8] = rB1;
            } else {
                *(bf16x8_t*)&Bs[buf ^ 1][(sub * 128 + row) * 8] = cvt8(rf0a, rf0b);
                *(bf16x8_t*)&Bs[buf ^ 1][((sub + 2) * 128 + row) * 8] = cvt8(rf1a, rf1b);
            }
        }
        if (s + 2 < 8) {   // 2-slab-deep global prefetch
            int k0 = (s + 2) * 32;
            rA0 = *(const bf16x8_t*)(gA + k0);
            rA1 = *(const bf16x8_t*)(gA + k0 + 16);
            if (BF16B) {
                rB0 = *(const bf16x8_t*)(gBb + k0);
                rB1 = *(const bf16x8_t*)(gBb + k0 + 16);
            } else {
                rf0a = ((const float4*)(gBf + k0))[0];      rf0b = ((const float4*)(gBf + k0))[1];
                rf1a = ((const float4*)(gBf + k0 + 16))[0]; rf1b = ((const float4*)(gBf + k0 + 16))[1];
            }
        }
#pragma unroll
        for (int mt = 0; mt < 4; mt++)
#pragma unroll
            for (int nt = 0; nt < 4; nt++)
                acc[mt][nt] = __builtin_amdgcn_mfma_f32_16x16x32_bf16(a[mt], b[nt], acc[mt][nt], 0, 0, 0);
        barrier_lds();
    }

    // epilogue: bias + exp + rowsum; extract target logits inline
    int tg[16];
#pragma unroll
    for (int i = 0; i < 16; i++)
        tg[i] = tgt[wm + (i >> 2) * 16 + lh * 4 + (i & 3)];

    float rsum[16];
#pragma unroll
    for (int i = 0; i < 16; i++) rsum[i] = 0.f;
#pragma unroll
    for (int nt = 0; nt < 4; nt++) {
        int n = n0 + wn + nt * 16 + lr;
        float bias = bfc[n];
#pragma unroll
        for (int mt = 0; mt < 4; mt++)
#pragma unroll
            for (int r = 0; r < 4; r++) {
                float v = acc[mt][nt][r] + bias;
                rsum[mt * 4 + r] += __expf(v);
                if (tg[mt * 4 + r] == n)
                    TL[m0 + wm + mt * 16 + lh * 4 + r] = v;
            }
    }
#pragma unroll
    for (int m = 1; m < 16; m <<= 1)
#pragma unroll
        for (int i = 0; i < 16; i++) rsum[i] += __shfl_xor(rsum[i], m, 64);
    if (lr == 0) {
#pragma unroll
        for (int i = 0; i < 16; i++) {
            int r = m0 + wm + (i >> 2) * 16 + lh * 4 + (i & 3);
            atomicAdd(&S[r], rsum[i]);
        }
    }
}

// ---------------------------------------------------------------------------
// K4: loss = mean_r( log(S[r]) - TL[r] )
// ---------------------------------------------------------------------------
__global__ __launch_bounds__(256) void loss_kernel(
    const float* __restrict__ S,
    const float* __restrict__ TL,
    float* __restrict__ out)
{
    int tid = threadIdx.x;
    float p = 0.f;
    for (int i = tid; i < ROWS; i += 256) p += __logf(S[i]) - TL[i];
#pragma unroll
    for (int m = 1; m < 64; m <<= 1) p += __shfl_xor(p, m, 64);
    __shared__ float red[4];
    if ((tid & 63) == 0) red[tid >> 6] = p;
    __syncthreads();
    if (tid == 0)
        out[0] = (red[0] + red[1] + red[2] + red[3]) / (float)ROWS;
}

extern "C" void kernel_launch(void* const* d_in, const int* in_sizes, int n_in,
                              void* d_out, int out_size, void* d_ws, size_t ws_size,
                              hipStream_t stream)
{
    (void)in_sizes; (void)n_in; (void)out_size;
    const int*   inputs  = (const int*)d_in[0];
    const int*   targets = (const int*)d_in[1];
    const float* Wih = (const float*)d_in[2];
    const float* bih = (const float*)d_in[3];
    const float* Whh = (const float*)d_in[4];
    const float* bhh = (const float*)d_in[5];
    const float* Wfc = (const float*)d_in[6];
    const float* bfc = (const float*)d_in[7];

    float* S  = (float*)d_ws;                           // 4096 f32
    float* TL = S + ROWS;                               // 4096 f32
    float* xp = TL + ROWS;                              // [T][B][H] fp32, 4 MB
    __hip_bfloat16* hs = (__hip_bfloat16*)(xp + (size_t)SEQT * BATCH * HID); // 2 MB
    __hip_bfloat16* Wfcb = hs + (size_t)ROWS * HID;     // 32000x256 bf16, 16 MB

    const size_t need = (size_t)(2 * ROWS) * 4 + (size_t)ROWS * HID * 4
                      + (size_t)ROWS * HID * 2 + (size_t)VOCAB * HID * 2;
    const int use_bf16b = (ws_size >= need) ? 1 : 0;

    xproj_kernel<<<(SEQT * BATCH * HID) / 256, 256, 0, stream>>>(
        inputs, Wih, bih, bhh, Wfc, xp, S, Wfcb, use_bf16b);
    rnn_kernel<<<1, 512, 0, stream>>>(xp, Whh, hs);
    if (use_bf16b)
        fc_kernel<true><<<8192, 256, 0, stream>>>(hs, (const void*)Wfcb, bfc, targets, S, TL);
    else
        fc_kernel<false><<<8192, 256, 0, stream>>>(hs, (const void*)Wfc, bfc, targets, S, TL);
    loss_kernel<<<1, 256, 0, stream>>>(S, TL, (float*)d_out);
}